// Round 17
// baseline (634.066 us; speedup 1.0000x reference)
//
#include <hip/hip_runtime.h>
#include <cstddef>

#define Bb 8
#define Tt 24
#define Nn 512
#define Dd 128
#define Hh 8

typedef unsigned short u16;
using short8 = __attribute__((ext_vector_type(8))) short;
using f32x4  = __attribute__((ext_vector_type(4))) float;

__device__ __forceinline__ float b2f(u16 u) {
  union { unsigned u; float f; } w; w.u = ((unsigned)u) << 16; return w.f;
}
__device__ __forceinline__ u16 f2b(float f) {
  union { float f; unsigned u; } w; w.f = f;
  unsigned r = w.u + 0x7FFFu + ((w.u >> 16) & 1u);
  return (u16)(r >> 16);
}

// ---------------------------------------------------------------------------
// Shared 128x128-tile MFMA GEMM phase, BK=64.
// LDS tile [128 rows][64 k] bf16 = 16KB per buffer; byte ^ ((row&7)<<4).
// ---------------------------------------------------------------------------
__device__ __forceinline__ void mm_phase(const u16* __restrict__ A,
                                         const u16* __restrict__ BT,
                                         int K, int m0,
                                         u16* sA, u16* sB, f32x4 acc[4][4])
{
  const int tid = threadIdx.x;
  const int l = tid & 63, wid = tid >> 6;
  const int wm = (wid >> 1) << 6, wn = (wid & 1) << 6;
  int a_off[2][4], b_off[2][4];
#pragma unroll
  for (int kk = 0; kk < 2; ++kk)
#pragma unroll
    for (int i = 0; i < 4; ++i) {
      int ra = wm + i * 16 + (l & 15);
      a_off[kk][i] = ((ra << 7) + (kk << 6) + ((l >> 4) << 4)) ^ ((ra & 7) << 4);
      int rb = wn + i * 16 + (l & 15);
      b_off[kk][i] = ((rb << 7) + (kk << 6) + ((l >> 4) << 4)) ^ ((rb & 7) << 4);
    }
  const int srow = tid >> 3, schunk = tid & 7;
  int w_off[4];
#pragma unroll
  for (int j = 0; j < 4; ++j) {
    int r = srow + j * 32;
    w_off[j] = ((r << 7) + (schunk << 4)) ^ ((r & 7) << 4);
  }
  const int ke = schunk * 8;
  for (int k0 = 0; k0 < K; k0 += 64) {
    short8 a[4], b[4];
#pragma unroll
    for (int j = 0; j < 4; ++j) {
      a[j] = *(const short8*)(A + (size_t)(m0 + srow + j * 32) * K + k0 + ke);
      b[j] = *(const short8*)(BT + (size_t)(srow + j * 32) * K + k0 + ke);
    }
    __syncthreads();
#pragma unroll
    for (int j = 0; j < 4; ++j) {
      *(short8*)((char*)sA + w_off[j]) = a[j];
      *(short8*)((char*)sB + w_off[j]) = b[j];
    }
    __syncthreads();
#pragma unroll
    for (int kk = 0; kk < 2; ++kk) {
      short8 af[4], bf_[4];
#pragma unroll
      for (int i = 0; i < 4; ++i) {
        af[i]  = *(const short8*)((const char*)sA + a_off[kk][i]);
        bf_[i] = *(const short8*)((const char*)sB + b_off[kk][i]);
      }
#pragma unroll
      for (int mi = 0; mi < 4; ++mi)
#pragma unroll
        for (int ni = 0; ni < 4; ++ni)
          acc[mi][ni] = __builtin_amdgcn_mfma_f32_16x16x32_bf16(
              af[mi], bf_[ni], acc[mi][ni], 0, 0, 0);
    }
  }
}

// ---------------------------------------------------------------------------
// Generic GEMM: C = A@B (+bias,+relu), B given as BT[N][K]. 128x128 tile.
// ---------------------------------------------------------------------------
template <int OUTBF16, int RELU>
__device__ __forceinline__ void gemm_mfma_body(
    const u16* __restrict__ A, const u16* __restrict__ BT,
    const float* __restrict__ bias, void* __restrict__ Cv,
    int N, int K, int m0, int n0)
{
  __shared__ u16 sA[8192];
  __shared__ u16 sB[8192];
  f32x4 acc[4][4] = {};
  mm_phase(A, BT + (size_t)n0 * K, K, m0, sA, sB, acc);
  const int l = threadIdx.x & 63, wid = threadIdx.x >> 6;
  const int wm = (wid >> 1) << 6, wn = (wid & 1) << 6;
  const int cr = (l >> 4) << 2, cc = l & 15;
#pragma unroll
  for (int mi = 0; mi < 4; ++mi) {
    int rowb = m0 + wm + mi * 16 + cr;
#pragma unroll
    for (int ni = 0; ni < 4; ++ni) {
      int col = n0 + wn + ni * 16 + cc;
      float bb = bias ? bias[col] : 0.f;
#pragma unroll
      for (int r = 0; r < 4; ++r) {
        float v = acc[mi][ni][r] + bb;
        if (RELU) v = fmaxf(v, 0.f);
        size_t idx = (size_t)(rowb + r) * N + col;
        if (OUTBF16) ((u16*)Cv)[idx] = f2b(v);
        else         ((float*)Cv)[idx] = v;
      }
    }
  }
}

template <int OUTBF16, int RELU>
__global__ __launch_bounds__(256) void gemm_mfma_k(
    const u16* __restrict__ A, const u16* __restrict__ BT,
    const float* __restrict__ bias, void* __restrict__ C, int N, int K)
{
  gemm_mfma_body<OUTBF16, RELU>(A, BT, bias, C, N, K,
                                blockIdx.y * 128, blockIdx.x * 128);
}

// x1[bt] = graph[t] @ x[bt]
__global__ __launch_bounds__(256) void gemm_mfma_graph(
    const u16* __restrict__ g, const u16* __restrict__ xT, u16* __restrict__ x1)
{
  const int bt = blockIdx.z, t = bt % Tt;
  gemm_mfma_body<1, 0>(g + (size_t)t * Nn * Nn, xT + (size_t)bt * Dd * Nn,
                       nullptr, x1 + (size_t)bt * Nn * Dd,
                       Dd, Nn, blockIdx.y * 128, 0);
}

// ---------------------------------------------------------------------------
// Fused out-proj + pw (layer 0): att0 = cat@Wo+bo (bf16), gp0 = att0*pw (bf16)
// ---------------------------------------------------------------------------
__global__ __launch_bounds__(256) void gemm_og0(
    const u16* __restrict__ cat, const u16* __restrict__ outT, const float* __restrict__ ob,
    const u16* __restrict__ xb,  const u16* __restrict__ pwT,  const float* __restrict__ pb,
    u16* __restrict__ gp0, u16* __restrict__ att0)
{
  __shared__ u16 sA[8192], sB[8192];
  const int m0 = blockIdx.x * 128;
  f32x4 accP[4][4] = {};
  mm_phase(xb, pwT, 128, m0, sA, sB, accP);
  f32x4 accO[4][4] = {};
  mm_phase(cat, outT, 256, m0, sA, sB, accO);
  const int l = threadIdx.x & 63, wid = threadIdx.x >> 6;
  const int wm = (wid >> 1) << 6, wn = (wid & 1) << 6;
  const int cr = (l >> 4) << 2, cc = l & 15;
#pragma unroll
  for (int mi = 0; mi < 4; ++mi) {
    int rowb = m0 + wm + mi * 16 + cr;
#pragma unroll
    for (int ni = 0; ni < 4; ++ni) {
      int col = wn + ni * 16 + cc;
      float obv = ob[col], pbv = pb[col];
#pragma unroll
      for (int r = 0; r < 4; ++r) {
        size_t idx = (size_t)(rowb + r) * 128 + col;
        float attv = accO[mi][ni][r] + obv;
        float pwv  = accP[mi][ni][r] + pbv;
        att0[idx] = f2b(attv);
        gp0[idx] = f2b(attv * pwv);
      }
    }
  }
}

// ---------------------------------------------------------------------------
// Fused out-proj + pw + glo + LN1 (layer 1):
// h16 = LN(2x + gp0 + (cat@Wo+bo)*(att0@Wp+bp)*0.01)
// ---------------------------------------------------------------------------
__global__ __launch_bounds__(256) void gemm_og1(
    const u16* __restrict__ cat, const u16* __restrict__ outT, const float* __restrict__ ob,
    const u16* __restrict__ att0, const u16* __restrict__ pwT, const float* __restrict__ pb,
    const u16* __restrict__ gp0, const float* __restrict__ x,
    const float* __restrict__ g, const float* __restrict__ be,
    u16* __restrict__ h16)
{
  __shared__ __align__(16) u16 smem[128 * 136];
  __shared__ float sg[128], sbt[128];
  u16* sA = smem;
  u16* sB = smem + 8192;
  if (threadIdx.x < 128) { sg[threadIdx.x] = g[threadIdx.x]; sbt[threadIdx.x] = be[threadIdx.x]; }
  const int m0 = blockIdx.x * 128;
  f32x4 accP[4][4] = {};
  mm_phase(att0, pwT, 128, m0, sA, sB, accP);
  f32x4 accO[4][4] = {};
  mm_phase(cat, outT, 256, m0, sA, sB, accO);
  const int l = threadIdx.x & 63, wid = threadIdx.x >> 6;
  const int wm = (wid >> 1) << 6, wn = (wid & 1) << 6;
  const int cr = (l >> 4) << 2, cc = l & 15;
  __syncthreads();
#pragma unroll
  for (int mi = 0; mi < 4; ++mi) {
    int lrow = wm + mi * 16 + cr;
#pragma unroll
    for (int ni = 0; ni < 4; ++ni) {
      int col = wn + ni * 16 + cc;
      float obv = ob[col], pbv = pb[col];
#pragma unroll
      for (int r = 0; r < 4; ++r) {
        size_t idx = (size_t)(m0 + lrow + r) * 128 + col;
        float attv = accO[mi][ni][r] + obv;
        float pwv  = accP[mi][ni][r] + pbv;
        float hpre = 2.f * x[idx] + b2f(gp0[idx]) + attv * pwv * 0.01f;
        smem[(lrow + r) * 136 + col] = f2b(hpre);
      }
    }
  }
  __syncthreads();
  const int row = threadIdx.x >> 1, half = threadIdx.x & 1;
  const u16* rp = smem + row * 136 + half * 64;
  float s = 0.f, ss = 0.f;
#pragma unroll
  for (int j8 = 0; j8 < 8; ++j8) {
    short8 v = *(const short8*)(rp + j8 * 8);
#pragma unroll
    for (int j = 0; j < 8; ++j) { float f = b2f((u16)v[j]); s += f; ss += f * f; }
  }
  s += __shfl_xor(s, 1);
  ss += __shfl_xor(ss, 1);
  float mu = s * (1.f / 128.f);
  float rstd = rsqrtf(ss * (1.f / 128.f) - mu * mu + 1e-5f);
  size_t gbase = (size_t)(m0 + row) * 128 + half * 64;
#pragma unroll
  for (int j8 = 0; j8 < 8; ++j8) {
    short8 v = *(const short8*)(rp + j8 * 8);
    short8 o;
#pragma unroll
    for (int j = 0; j < 8; ++j) {
      int col = half * 64 + j8 * 8 + j;
      o[j] = (short)f2b((b2f((u16)v[j]) - mu) * rstd * sg[col] + sbt[col]);
    }
    *(short8*)(h16 + gbase + j8 * 8) = o;
  }
}

// ---------------------------------------------------------------------------
// Fused fc2 + LN2: out = LN(h16 + hid@fc2+b)
// ---------------------------------------------------------------------------
__global__ __launch_bounds__(256) void gemm_fc2ln(
    const u16* __restrict__ hid, const u16* __restrict__ fc2T, const float* __restrict__ fb,
    const u16* __restrict__ h16, const float* __restrict__ g, const float* __restrict__ be,
    float* __restrict__ out)
{
  __shared__ __align__(16) u16 smem[128 * 136];
  __shared__ float sg[128], sbt[128];
  u16* sA = smem;
  u16* sB = smem + 8192;
  if (threadIdx.x < 128) { sg[threadIdx.x] = g[threadIdx.x]; sbt[threadIdx.x] = be[threadIdx.x]; }
  const int m0 = blockIdx.x * 128;
  f32x4 accO[4][4] = {};
  mm_phase(hid, fc2T, 256, m0, sA, sB, accO);
  const int l = threadIdx.x & 63, wid = threadIdx.x >> 6;
  const int wm = (wid >> 1) << 6, wn = (wid & 1) << 6;
  const int cr = (l >> 4) << 2, cc = l & 15;
  __syncthreads();
#pragma unroll
  for (int mi = 0; mi < 4; ++mi) {
    int lrow = wm + mi * 16 + cr;
#pragma unroll
    for (int ni = 0; ni < 4; ++ni) {
      int col = wn + ni * 16 + cc;
      float fbv = fb[col];
#pragma unroll
      for (int r = 0; r < 4; ++r) {
        size_t idx = (size_t)(m0 + lrow + r) * 128 + col;
        float hpre = b2f(h16[idx]) + accO[mi][ni][r] + fbv;
        smem[(lrow + r) * 136 + col] = f2b(hpre);
      }
    }
  }
  __syncthreads();
  const int row = threadIdx.x >> 1, half = threadIdx.x & 1;
  const u16* rp = smem + row * 136 + half * 64;
  float s = 0.f, ss = 0.f;
#pragma unroll
  for (int j8 = 0; j8 < 8; ++j8) {
    short8 v = *(const short8*)(rp + j8 * 8);
#pragma unroll
    for (int j = 0; j < 8; ++j) { float f = b2f((u16)v[j]); s += f; ss += f * f; }
  }
  s += __shfl_xor(s, 1);
  ss += __shfl_xor(ss, 1);
  float mu = s * (1.f / 128.f);
  float rstd = rsqrtf(ss * (1.f / 128.f) - mu * mu + 1e-5f);
  size_t gbase = (size_t)(m0 + row) * 128 + half * 64;
#pragma unroll
  for (int j8 = 0; j8 < 8; ++j8) {
    short8 v = *(const short8*)(rp + j8 * 8);
    float4 o0, o1;
#pragma unroll
    for (int j = 0; j < 8; ++j) {
      int col = half * 64 + j8 * 8 + j;
      float y = (b2f((u16)v[j]) - mu) * rstd * sg[col] + sbt[col];
      if (j < 4) ((float*)&o0)[j] = y; else ((float*)&o1)[j - 4] = y;
    }
    *(float4*)(out + gbase + j8 * 8) = o0;
    *(float4*)(out + gbase + j8 * 8 + 4) = o1;
  }
}

// ---------------------------------------------------------------------------
// qknorm (q only): per (row, head g): inv = 1/max(||q_g||,1e-12)
// ---------------------------------------------------------------------------
__global__ __launch_bounds__(256) void qknorm(const u16* __restrict__ qkv,
                                              float* __restrict__ inv, size_t nidx)
{
  size_t idx = (size_t)blockIdx.x * 256 + threadIdx.x;
  if (idx >= nidx) return;
  size_t row = idx >> 3;
  int g = (int)(idx & 7);
  const u16* p = qkv + row * 384 + g * 16;
  short8 a = *(const short8*)p;
  short8 b = *(const short8*)(p + 8);
  float ss = 0.f;
#pragma unroll
  for (int j = 0; j < 8; ++j) {
    float f0 = b2f((u16)a[j]), f1 = b2f((u16)b[j]);
    ss += f0 * f0 + f1 * f1;
  }
  inv[idx] = 1.f / fmaxf(sqrtf(ss), 1e-12f);
}

__global__ __launch_bounds__(256) void cvt_f32_bf16(const float* __restrict__ src,
                                                    u16* __restrict__ dst, size_t n8)
{
  size_t i = (size_t)blockIdx.x * 256 + threadIdx.x;
  if (i >= n8) return;
  const float4* s = (const float4*)src;
  float4 u = s[i * 2], v = s[i * 2 + 1];
  short8 o;
  o[0] = (short)f2b(u.x); o[1] = (short)f2b(u.y);
  o[2] = (short)f2b(u.z); o[3] = (short)f2b(u.w);
  o[4] = (short)f2b(v.x); o[5] = (short)f2b(v.y);
  o[6] = (short)f2b(v.z); o[7] = (short)f2b(v.w);
  *(short8*)(dst + i * 8) = o;
}

__global__ __launch_bounds__(256) void transpose_cvt(const float* __restrict__ src,
                                                     u16* __restrict__ dst,
                                                     int R, int C)
{
  __shared__ u16 tile[64][65];
  const int tid = threadIdx.x;
  src += (size_t)blockIdx.z * R * C;
  dst += (size_t)blockIdx.z * R * C;
  const int c0 = blockIdx.x * 64, r0 = blockIdx.y * 64;
  const int tx = tid & 63, ty = tid >> 6;
#pragma unroll
  for (int i = 0; i < 64; i += 4)
    tile[ty + i][tx] = f2b(src[(size_t)(r0 + ty + i) * C + c0 + tx]);
  __syncthreads();
#pragma unroll
  for (int i = 0; i < 64; i += 4)
    dst[(size_t)(c0 + ty + i) * R + r0 + tx] = tile[tx][ty + i];
}

// x (f32 [512][128] per bt) -> xb (bf16) AND xT (bf16 transposed)
__global__ __launch_bounds__(256) void cvt_transpose_x(const float* __restrict__ src,
                                                       u16* __restrict__ xb,
                                                       u16* __restrict__ xT)
{
  __shared__ u16 tile[64][65];
  const int tid = threadIdx.x;
  const size_t zo = (size_t)blockIdx.z * Nn * Dd;
  src += zo; xb += zo; xT += zo;
  const int c0 = blockIdx.x * 64, r0 = blockIdx.y * 64;
  const int tx = tid & 63, ty = tid >> 6;
#pragma unroll
  for (int i = 0; i < 64; i += 4) {
    u16 b = f2b(src[(size_t)(r0 + ty + i) * Dd + c0 + tx]);
    tile[ty + i][tx] = b;
    xb[(size_t)(r0 + ty + i) * Dd + c0 + tx] = b;
  }
  __syncthreads();
#pragma unroll
  for (int i = 0; i < 64; i += 4)
    xT[(size_t)(c0 + ty + i) * Nn + r0 + tx] = tile[tx][ty + i];
}

// ---------------------------------------------------------------------------
// Spatial stats via MFMA (k-norm inline): kvs2[bt][h][d][m] (transposed for
// float4 apply-side reads); ksum[m].
// ---------------------------------------------------------------------------
__global__ __launch_bounds__(256) void spatial_stats(const u16* __restrict__ qkv,
                                                     float* __restrict__ kvs2,
                                                     float* __restrict__ ksum)
{
  __shared__ u16 sKT[16 * 512];
  __shared__ u16 sVT[16 * 512];
  __shared__ float red[4][16][16];
  __shared__ float red2[4][16];
  const int bt = blockIdx.x, h = blockIdx.y;
  const int tid = threadIdx.x;

  u16 kr[2][16], vr[2][16];
#pragma unroll
  for (int r = 0; r < 2; ++r) {
    int n = tid * 2 + r;
    size_t base = ((size_t)bt * 512 + n) * 384;
    short8 k0 = *(const short8*)(qkv + base + 128 + h * 16);
    short8 k1 = *(const short8*)(qkv + base + 136 + h * 16);
    short8 v0 = *(const short8*)(qkv + base + 256 + h * 16);
    short8 v1 = *(const short8*)(qkv + base + 264 + h * 16);
    float kf[16];
    float ssum = 0.f;
#pragma unroll
    for (int j = 0; j < 8; ++j) {
      kf[j] = b2f((u16)k0[j]); kf[j + 8] = b2f((u16)k1[j]);
      vr[r][j] = (u16)v0[j];   vr[r][j + 8] = (u16)v1[j];
      ssum += kf[j] * kf[j] + kf[j + 8] * kf[j + 8];
    }
    float inv = 1.f / fmaxf(sqrtf(ssum), 1e-12f);
#pragma unroll
    for (int j = 0; j < 16; ++j) kr[r][j] = f2b(kf[j] * inv);
  }
#pragma unroll
  for (int m = 0; m < 16; ++m) {
    unsigned pk = (unsigned)kr[0][m] | ((unsigned)kr[1][m] << 16);
    unsigned pv = (unsigned)vr[0][m] | ((unsigned)vr[1][m] << 16);
    int wa = ((m << 10) + (tid << 2)) ^ ((m & 7) << 4);
    *(unsigned*)((char*)sKT + wa) = pk;
    *(unsigned*)((char*)sVT + wa) = pv;
  }
  __syncthreads();

  const int l = tid & 63, w = tid >> 6;
  const int fr = l & 15, tq = l >> 4;
  short8 ones;
#pragma unroll
  for (int j = 0; j < 8; ++j) ones[j] = (short)0x3F80;
  f32x4 acc = {}, acs = {};
#pragma unroll
  for (int kk = 0; kk < 4; ++kk) {
    int noff = w * 128 + kk * 32 + tq * 8;
    int ra = ((fr << 10) + (noff << 1)) ^ ((fr & 7) << 4);
    short8 afr = *(const short8*)((const char*)sKT + ra);
    short8 bfr = *(const short8*)((const char*)sVT + ra);
    acc = __builtin_amdgcn_mfma_f32_16x16x32_bf16(afr, bfr, acc, 0, 0, 0);
    acs = __builtin_amdgcn_mfma_f32_16x16x32_bf16(afr, ones, acs, 0, 0, 0);
  }
#pragma unroll
  for (int r = 0; r < 4; ++r) red[w][tq * 4 + r][fr] = acc[r];
  if (fr == 0) {
#pragma unroll
    for (int r = 0; r < 4; ++r) red2[w][tq * 4 + r] = acs[r];
  }
  __syncthreads();
  const size_t o = (size_t)bt * 8 + h;
  {
    int m = tid >> 4, d = tid & 15;
    float s = red[0][m][d] + red[1][m][d] + red[2][m][d] + red[3][m][d];
    kvs2[o * 256 + d * 16 + m] = s;   // [d][m] layout for float4 apply reads
  }
  if (tid < 16) {
    float s = red2[0][tid] + red2[1][tid] + red2[2][tid] + red2[3][tid];
    ksum[o * 16 + tid] = s;
  }
}

// ---------------------------------------------------------------------------
// Temporal stats via MFMA (k-norm inline via paired shfl): kvt[b,n][m][c].
// ---------------------------------------------------------------------------
__global__ __launch_bounds__(256) void temporal_stats(const u16* __restrict__ qkv,
                                                      float* __restrict__ kvt,
                                                      float* __restrict__ kst)
{
  __shared__ u16 sKT[128 * 32];
  __shared__ u16 sVT[128 * 32];
  const int nn = blockIdx.x, b = blockIdx.y;
  const int tid = threadIdx.x;
  if (tid < 128) {
    short8 z = {};
    int wa = ((tid << 6) + 48) ^ ((tid & 3) << 4);
    *(short8*)((char*)sKT + wa) = z;
    *(short8*)((char*)sVT + wa) = z;
  }
  for (int idx = tid; idx < 384; idx += 256) {
    int t = idx >> 4, c8 = idx & 15;
    size_t rowg = ((size_t)(b * 24 + t) * 512) + nn;
    short8 kv = *(const short8*)(qkv + rowg * 384 + 128 + c8 * 8);
    short8 vv = *(const short8*)(qkv + rowg * 384 + 256 + c8 * 8);
    float kf[8];
    float ssum = 0.f;
#pragma unroll
    for (int j = 0; j < 8; ++j) { kf[j] = b2f((u16)kv[j]); ssum += kf[j] * kf[j]; }
    ssum += __shfl_xor(ssum, 1);   // partner lane = other half of this head
    float inv = 1.f / fmaxf(sqrtf(ssum), 1e-12f);
#pragma unroll
    for (int j = 0; j < 8; ++j) {
      int c = c8 * 8 + j;
      int wa = ((c << 6) + (t << 1)) ^ ((c & 3) << 4);
      *(u16*)((char*)sKT + wa) = f2b(kf[j] * inv);
      *(u16*)((char*)sVT + wa) = (u16)vv[j];
    }
  }
  __syncthreads();
  const int l = tid & 63, w = tid >> 6;
  const int fr = l & 15, tq = l >> 4;
  const size_t nb = (size_t)b * 512 + nn;
  short8 ones;
#pragma unroll
  for (int j = 0; j < 8; ++j) ones[j] = (short)0x3F80;
#pragma unroll
  for (int hi = 0; hi < 2; ++hi) {
    int h = w * 2 + hi;
    int c = h * 16 + fr;
    int ra = ((c << 6) + (tq << 4)) ^ ((c & 3) << 4);
    short8 afr = *(const short8*)((const char*)sKT + ra);
    short8 bfr = *(const short8*)((const char*)sVT + ra);
    f32x4 z = {};
    f32x4 acc = __builtin_amdgcn_mfma_f32_16x16x32_bf16(afr, bfr, z, 0, 0, 0);
    f32x4 acs = __builtin_amdgcn_mfma_f32_16x16x32_bf16(afr, ones, z, 0, 0, 0);
#pragma unroll
    for (int r = 0; r < 4; ++r)
      kvt[nb * 2048 + (size_t)(tq * 4 + r) * 128 + h * 16 + fr] = acc[r];
    if (fr == 0) {
#pragma unroll
      for (int r = 0; r < 4; ++r)
        kst[(nb * 8 + h) * 16 + tq * 4 + r] = acs[r];
    }
  }
}

// ---------------------------------------------------------------------------
// Apply: grid (Nn, CB, 3); block = 2 t-halves x 128 cl; both outputs/thread.
// kvs2 read as 4x float4 ([d][m] layout); denominators via rcpf.
// ---------------------------------------------------------------------------
__global__ __launch_bounds__(256) void attn_apply(const u16* __restrict__ qkv,
                                                  const float* __restrict__ qkn,
                                                  const float* __restrict__ kvs2,
                                                  const float* __restrict__ kss,
                                                  const float* __restrict__ kvt,
                                                  const float* __restrict__ kst,
                                                  u16* __restrict__ out_cat)
{
  __shared__ float s_kvt[2048];
  __shared__ float s_kst[8][16];
  const int nn = blockIdx.x, b = blockIdx.y;
  const int tid = threadIdx.x;
  const size_t nb = (size_t)b * 512 + nn;
  for (int i = tid; i < 2048; i += 256) s_kvt[i] = kvt[nb * 2048 + i];
  if (tid < 128) s_kst[tid >> 4][tid & 15] = kst[nb * 128 + tid];
  __syncthreads();
  const int sub = tid >> 7, cl = tid & 127;
  const int hh = cl >> 4, d = cl & 15;
  const int tbase = blockIdx.z * 8 + sub * 4;
  const float kst_hd = s_kst[hh][d];
  for (int ti = 0; ti < 4; ++ti) {
    const int t = tbase + ti;
    const size_t row = ((size_t)(b * 24 + t) * 512) + nn;
    const u16* qp = qkv + row * 384 + hh * 16;
    short8 q0 = *(const short8*)qp;
    short8 q1 = *(const short8*)(qp + 8);
    const float inv = qkn[row * 8 + hh];
    float qf[16];
#pragma unroll
    for (int j = 0; j < 8; ++j) {
      qf[j] = b2f((u16)q0[j]);
      qf[j + 8] = b2f((u16)q1[j]);
    }
    const size_t hb = (size_t)(b * 24 + t) * 8 + hh;
    // spatial numerator: kvs2 row [d][m] = 16 consecutive floats
    const float4* M4 = (const float4*)(kvs2 + hb * 256 + d * 16);
    float accs = 0.f, acct = 0.f;
#pragma unroll
    for (int i = 0; i < 4; ++i) {
      float4 m = M4[i];
      accs = fmaf(qf[i * 4], m.x, fmaf(qf[i * 4 + 1], m.y,
             fmaf(qf[i * 4 + 2], m.z, fmaf(qf[i * 4 + 3], m.w, accs))));
    }
#pragma unroll
    for (int mI = 0; mI < 16; ++mI)
      acct = fmaf(qf[mI], s_kvt[mI * 128 + cl], acct);
    float dps = qf[d] * kss[hb * 16 + d];
    float dpt = qf[d] * kst_hd;
    dps += __shfl_xor(dps, 1);  dpt += __shfl_xor(dpt, 1);
    dps += __shfl_xor(dps, 2);  dpt += __shfl_xor(dpt, 2);
    dps += __shfl_xor(dps, 4);  dpt += __shfl_xor(dpt, 4);
    dps += __shfl_xor(dps, 8);  dpt += __shfl_xor(dpt, 8);
    float vv = b2f(qkv[row * 384 + 256 + cl]);
    float rs = __builtin_amdgcn_rcpf(fmaf(dps, inv, 512.f));
    float rt = __builtin_amdgcn_rcpf(fmaf(dpt, inv, 24.f));
    out_cat[row * 256 + cl]       = f2b(fmaf(accs, inv, 512.f * vv) * rs);
    out_cat[row * 256 + 128 + cl] = f2b(fmaf(acct, inv, 24.f * vv) * rt);
  }
}

extern "C" void kernel_launch(void* const* d_in, const int* in_sizes, int n_in,
                              void* d_out, int out_size, void* d_ws, size_t ws_size,
                              hipStream_t stream)
{
  const float* x      = (const float*)d_in[0];
  const float* graph  = (const float*)d_in[1];
  const float* qkv_w0 = (const float*)d_in[2];
  const float* out_w0 = (const float*)d_in[3];
  const float* out_b0 = (const float*)d_in[4];
  const float* pw_w0  = (const float*)d_in[5];
  const float* pw_b0  = (const float*)d_in[6];
  const float* qkv_w1 = (const float*)d_in[7];
  const float* out_w1 = (const float*)d_in[8];
  const float* out_b1 = (const float*)d_in[9];
  const float* pw_w1  = (const float*)d_in[10];
  const float* pw_b1  = (const float*)d_in[11];
  const float* fc1_w  = (const float*)d_in[12];
  const float* fc1_b  = (const float*)d_in[13];
  const float* fc2_w  = (const float*)d_in[14];
  const float* fc2_b  = (const float*)d_in[15];
  const float* ln1_g  = (const float*)d_in[16];
  const float* ln1_b  = (const float*)d_in[17];
  const float* ln2_g  = (const float*)d_in[18];
  const float* ln2_b  = (const float*)d_in[19];
  float* out = (float*)d_out;

  auto al = [](size_t v) { return (v + 255) & ~(size_t)255; };
  const size_t Rb = 12288;
  const size_t fixed = al((size_t)Tt * Nn * Nn * 2) + 2 * al((size_t)384 * 128 * 2)
                     + 2 * al((size_t)128 * 256 * 2) + 2 * al((size_t)128 * 128 * 2)
                     + al((size_t)256 * 128 * 2) + al((size_t)128 * 256 * 2);
  const size_t perb = al(Rb * 768) + al(Rb * 512) + 4 * al(Rb * 256) + al(Rb * 32)
                    + al((size_t)Tt * 8 * 256 * 4) + al((size_t)Tt * 8 * 16 * 4)
                    + al((size_t)Nn * 8 * 256 * 4) + al((size_t)Nn * 8 * 16 * 4);
  int CB = 8;
  while (CB > 1 && fixed + (size_t)CB * perb > ws_size) CB >>= 1;
  const size_t Mc = (size_t)CB * Rb;

  char* cur = (char*)d_ws;
  auto alloc = [&](size_t bytes) { char* p = cur; cur += (bytes + 255) & ~(size_t)255; return p; };
  u16* g_b16 = (u16*)alloc((size_t)Tt * Nn * Nn * 2);
  u16* qkvT0 = (u16*)alloc((size_t)384 * 128 * 2);
  u16* qkvT1 = (u16*)alloc((size_t)384 * 128 * 2);
  u16* outT0 = (u16*)alloc((size_t)128 * 256 * 2);
  u16* outT1 = (u16*)alloc((size_t)128 * 256 * 2);
  u16* pwT0  = (u16*)alloc((size_t)128 * 128 * 2);
  u16* pwT1  = (u16*)alloc((size_t)128 * 128 * 2);
  u16* fc1T  = (u16*)alloc((size_t)256 * 128 * 2);
  u16* fc2T  = (u16*)alloc((size_t)128 * 256 * 2);
  u16* qkvb  = (u16*)alloc(Mc * 768);
  u16* catb  = (u16*)alloc(Mc * 512);
  u16* x1b   = (u16*)alloc(Mc * 256);
  u16* att0  = (u16*)alloc(Mc * 256);
  u16* xb    = (u16*)alloc(Mc * 256);
  u16* xTgp  = (u16*)alloc(Mc * 256);
  float* qkn = (float*)alloc(Mc * 32);
  float* kvs = (float*)alloc((size_t)CB * Tt * 8 * 256 * 4);
  float* kss = (float*)alloc((size_t)CB * Tt * 8 * 16 * 4);
  float* kvt = (float*)alloc((size_t)CB * Nn * 8 * 256 * 4);
  float* kst = (float*)alloc((size_t)CB * Nn * 8 * 16 * 4);

  dim3 blk(256);
  cvt_f32_bf16<<<dim3((Tt * Nn * Nn / 8 + 255) / 256), blk, 0, stream>>>(
      graph, g_b16, (size_t)Tt * Nn * Nn / 8);
  transpose_cvt<<<dim3(6, 2, 1), blk, 0, stream>>>(qkv_w0, qkvT0, 128, 384);
  transpose_cvt<<<dim3(6, 2, 1), blk, 0, stream>>>(qkv_w1, qkvT1, 128, 384);
  transpose_cvt<<<dim3(2, 4, 1), blk, 0, stream>>>(out_w0, outT0, 256, 128);
  transpose_cvt<<<dim3(2, 4, 1), blk, 0, stream>>>(out_w1, outT1, 256, 128);
  transpose_cvt<<<dim3(2, 2, 1), blk, 0, stream>>>(pw_w0, pwT0, 128, 128);
  transpose_cvt<<<dim3(2, 2, 1), blk, 0, stream>>>(pw_w1, pwT1, 128, 128);
  transpose_cvt<<<dim3(4, 2, 1), blk, 0, stream>>>(fc1_w, fc1T, 128, 256);
  transpose_cvt<<<dim3(2, 4, 1), blk, 0, stream>>>(fc2_w, fc2T, 256, 128);

  const int MB = (int)(Mc / 128);
  const int nchunk = Bb / CB;
  for (int c = 0; c < nchunk; ++c) {
    const size_t off = (size_t)c * Mc * 128;
    const float* xc = x + off;
    float* outc = out + off;

    cvt_transpose_x<<<dim3(2, 8, CB * Tt), blk, 0, stream>>>(xc, xb, xTgp);
    gemm_mfma_graph<<<dim3(1, 4, CB * Tt), blk, 0, stream>>>(g_b16, xTgp, x1b);

    // ----- layer 0 -----
    gemm_mfma_k<1, 0><<<dim3(3, MB), blk, 0, stream>>>(xb, qkvT0, nullptr, qkvb, 384, 128);
    qknorm<<<dim3((unsigned)(Mc / 32)), blk, 0, stream>>>(qkvb, qkn, Mc * 8);
    spatial_stats<<<dim3(CB * Tt, Hh), blk, 0, stream>>>(qkvb, kvs, kss);
    temporal_stats<<<dim3(Nn, CB), blk, 0, stream>>>(qkvb, kvt, kst);
    attn_apply<<<dim3(Nn, CB, 3), blk, 0, stream>>>(qkvb, qkn, kvs, kss, kvt, kst, catb);
    gemm_og0<<<dim3(MB), blk, 0, stream>>>(catb, outT0, out_b0, xb, pwT0, pw_b0,
                                           xTgp, att0);   // gp0 = xTgp (xT dead)

    // ----- layer 1 -----
    gemm_mfma_k<1, 0><<<dim3(3, MB), blk, 0, stream>>>(x1b, qkvT1, nullptr, qkvb, 384, 128);
    qknorm<<<dim3((unsigned)(Mc / 32)), blk, 0, stream>>>(qkvb, qkn, Mc * 8);
    spatial_stats<<<dim3(CB * Tt, Hh), blk, 0, stream>>>(qkvb, kvs, kss);
    temporal_stats<<<dim3(Nn, CB), blk, 0, stream>>>(qkvb, kvt, kst);
    attn_apply<<<dim3(Nn, CB, 3), blk, 0, stream>>>(qkvb, qkn, kvs, kss, kvt, kst, catb);
    u16* h16 = qkvb;   // qkvb dead after apply1
    gemm_og1<<<dim3(MB), blk, 0, stream>>>(catb, outT1, out_b1, att0, pwT1, pw_b1,
                                           xTgp, xc, ln1_g, ln1_b, h16);

    // ----- MLP + LN2 -----
    gemm_mfma_k<1, 1><<<dim3(2, MB), blk, 0, stream>>>(h16, fc1T, fc1_b, catb, 256, 128);
    gemm_fc2ln<<<dim3(MB), blk, 0, stream>>>(catb, fc2T, fc2_b, h16, ln2_g, ln2_b, outc);
  }

  (void)in_sizes; (void)n_in; (void)out_size;
}

// Round 18
// 573.336 us; speedup vs baseline: 1.1059x; 1.1059x over previous
//
#include <hip/hip_runtime.h>
#include <cstddef>

#define Bb 8
#define Tt 24
#define Nn 512
#define Dd 128
#define Hh 8

typedef unsigned short u16;
using short8 = __attribute__((ext_vector_type(8))) short;
using f32x4  = __attribute__((ext_vector_type(4))) float;

__device__ __forceinline__ float b2f(u16 u) {
  union { unsigned u; float f; } w; w.u = ((unsigned)u) << 16; return w.f;
}
__device__ __forceinline__ u16 f2b(float f) {
  union { float f; unsigned u; } w; w.f = f;
  unsigned r = w.u + 0x7FFFu + ((w.u >> 16) & 1u);
  return (u16)(r >> 16);
}

// ---------------------------------------------------------------------------
// Shared 128x128-tile MFMA GEMM phase, BK=64.
// LDS tile [128 rows][64 k] bf16 = 16KB per buffer; byte ^ ((row&7)<<4).
// ---------------------------------------------------------------------------
__device__ __forceinline__ void mm_phase(const u16* __restrict__ A,
                                         const u16* __restrict__ BT,
                                         int K, int m0,
                                         u16* sA, u16* sB, f32x4 acc[4][4])
{
  const int tid = threadIdx.x;
  const int l = tid & 63, wid = tid >> 6;
  const int wm = (wid >> 1) << 6, wn = (wid & 1) << 6;
  int a_off[2][4], b_off[2][4];
#pragma unroll
  for (int kk = 0; kk < 2; ++kk)
#pragma unroll
    for (int i = 0; i < 4; ++i) {
      int ra = wm + i * 16 + (l & 15);
      a_off[kk][i] = ((ra << 7) + (kk << 6) + ((l >> 4) << 4)) ^ ((ra & 7) << 4);
      int rb = wn + i * 16 + (l & 15);
      b_off[kk][i] = ((rb << 7) + (kk << 6) + ((l >> 4) << 4)) ^ ((rb & 7) << 4);
    }
  const int srow = tid >> 3, schunk = tid & 7;
  int w_off[4];
#pragma unroll
  for (int j = 0; j < 4; ++j) {
    int r = srow + j * 32;
    w_off[j] = ((r << 7) + (schunk << 4)) ^ ((r & 7) << 4);
  }
  const int ke = schunk * 8;
  for (int k0 = 0; k0 < K; k0 += 64) {
    short8 a[4], b[4];
#pragma unroll
    for (int j = 0; j < 4; ++j) {
      a[j] = *(const short8*)(A + (size_t)(m0 + srow + j * 32) * K + k0 + ke);
      b[j] = *(const short8*)(BT + (size_t)(srow + j * 32) * K + k0 + ke);
    }
    __syncthreads();
#pragma unroll
    for (int j = 0; j < 4; ++j) {
      *(short8*)((char*)sA + w_off[j]) = a[j];
      *(short8*)((char*)sB + w_off[j]) = b[j];
    }
    __syncthreads();
#pragma unroll
    for (int kk = 0; kk < 2; ++kk) {
      short8 af[4], bf_[4];
#pragma unroll
      for (int i = 0; i < 4; ++i) {
        af[i]  = *(const short8*)((const char*)sA + a_off[kk][i]);
        bf_[i] = *(const short8*)((const char*)sB + b_off[kk][i]);
      }
#pragma unroll
      for (int mi = 0; mi < 4; ++mi)
#pragma unroll
        for (int ni = 0; ni < 4; ++ni)
          acc[mi][ni] = __builtin_amdgcn_mfma_f32_16x16x32_bf16(
              af[mi], bf_[ni], acc[mi][ni], 0, 0, 0);
    }
  }
}

// ---------------------------------------------------------------------------
// Generic GEMM: C = A@B (+bias,+relu), B given as BT[N][K]. 128x128 tile.
// ---------------------------------------------------------------------------
template <int OUTBF16, int RELU>
__device__ __forceinline__ void gemm_mfma_body(
    const u16* __restrict__ A, const u16* __restrict__ BT,
    const float* __restrict__ bias, void* __restrict__ Cv,
    int N, int K, int m0, int n0)
{
  __shared__ u16 sA[8192];
  __shared__ u16 sB[8192];
  f32x4 acc[4][4] = {};
  mm_phase(A, BT + (size_t)n0 * K, K, m0, sA, sB, acc);
  const int l = threadIdx.x & 63, wid = threadIdx.x >> 6;
  const int wm = (wid >> 1) << 6, wn = (wid & 1) << 6;
  const int cr = (l >> 4) << 2, cc = l & 15;
#pragma unroll
  for (int mi = 0; mi < 4; ++mi) {
    int rowb = m0 + wm + mi * 16 + cr;
#pragma unroll
    for (int ni = 0; ni < 4; ++ni) {
      int col = n0 + wn + ni * 16 + cc;
      float bb = bias ? bias[col] : 0.f;
#pragma unroll
      for (int r = 0; r < 4; ++r) {
        float v = acc[mi][ni][r] + bb;
        if (RELU) v = fmaxf(v, 0.f);
        size_t idx = (size_t)(rowb + r) * N + col;
        if (OUTBF16) ((u16*)Cv)[idx] = f2b(v);
        else         ((float*)Cv)[idx] = v;
      }
    }
  }
}

template <int OUTBF16, int RELU>
__global__ __launch_bounds__(256) void gemm_mfma_k(
    const u16* __restrict__ A, const u16* __restrict__ BT,
    const float* __restrict__ bias, void* __restrict__ C, int N, int K)
{
  gemm_mfma_body<OUTBF16, RELU>(A, BT, bias, C, N, K,
                                blockIdx.y * 128, blockIdx.x * 128);
}

// x1[bt] = graph[t] @ x[bt]
__global__ __launch_bounds__(256) void gemm_mfma_graph(
    const u16* __restrict__ g, const u16* __restrict__ xT, u16* __restrict__ x1)
{
  const int bt = blockIdx.z, t = bt % Tt;
  gemm_mfma_body<1, 0>(g + (size_t)t * Nn * Nn, xT + (size_t)bt * Dd * Nn,
                       nullptr, x1 + (size_t)bt * Nn * Dd,
                       Dd, Nn, blockIdx.y * 128, 0);
}

// ---------------------------------------------------------------------------
// Fused out-proj + pw (layer 0): att0 = cat@Wo+bo (bf16), gp0 = att0*pw (bf16)
// ---------------------------------------------------------------------------
__global__ __launch_bounds__(256) void gemm_og0(
    const u16* __restrict__ cat, const u16* __restrict__ outT, const float* __restrict__ ob,
    const u16* __restrict__ xb,  const u16* __restrict__ pwT,  const float* __restrict__ pb,
    u16* __restrict__ gp0, u16* __restrict__ att0)
{
  __shared__ u16 sA[8192], sB[8192];
  const int m0 = blockIdx.x * 128;
  f32x4 accP[4][4] = {};
  mm_phase(xb, pwT, 128, m0, sA, sB, accP);
  f32x4 accO[4][4] = {};
  mm_phase(cat, outT, 256, m0, sA, sB, accO);
  const int l = threadIdx.x & 63, wid = threadIdx.x >> 6;
  const int wm = (wid >> 1) << 6, wn = (wid & 1) << 6;
  const int cr = (l >> 4) << 2, cc = l & 15;
#pragma unroll
  for (int mi = 0; mi < 4; ++mi) {
    int rowb = m0 + wm + mi * 16 + cr;
#pragma unroll
    for (int ni = 0; ni < 4; ++ni) {
      int col = wn + ni * 16 + cc;
      float obv = ob[col], pbv = pb[col];
#pragma unroll
      for (int r = 0; r < 4; ++r) {
        size_t idx = (size_t)(rowb + r) * 128 + col;
        float attv = accO[mi][ni][r] + obv;
        float pwv  = accP[mi][ni][r] + pbv;
        att0[idx] = f2b(attv);
        gp0[idx] = f2b(attv * pwv);
      }
    }
  }
}

// ---------------------------------------------------------------------------
// Fused out-proj + pw + glo + LN1 (layer 1):
// h16 = LN(2x + gp0 + (cat@Wo+bo)*(att0@Wp+bp)*0.01)
// ---------------------------------------------------------------------------
__global__ __launch_bounds__(256) void gemm_og1(
    const u16* __restrict__ cat, const u16* __restrict__ outT, const float* __restrict__ ob,
    const u16* __restrict__ att0, const u16* __restrict__ pwT, const float* __restrict__ pb,
    const u16* __restrict__ gp0, const float* __restrict__ x,
    const float* __restrict__ g, const float* __restrict__ be,
    u16* __restrict__ h16)
{
  __shared__ __align__(16) u16 smem[128 * 136];
  __shared__ float sg[128], sbt[128];
  u16* sA = smem;
  u16* sB = smem + 8192;
  if (threadIdx.x < 128) { sg[threadIdx.x] = g[threadIdx.x]; sbt[threadIdx.x] = be[threadIdx.x]; }
  const int m0 = blockIdx.x * 128;
  f32x4 accP[4][4] = {};
  mm_phase(att0, pwT, 128, m0, sA, sB, accP);
  f32x4 accO[4][4] = {};
  mm_phase(cat, outT, 256, m0, sA, sB, accO);
  const int l = threadIdx.x & 63, wid = threadIdx.x >> 6;
  const int wm = (wid >> 1) << 6, wn = (wid & 1) << 6;
  const int cr = (l >> 4) << 2, cc = l & 15;
  __syncthreads();
#pragma unroll
  for (int mi = 0; mi < 4; ++mi) {
    int lrow = wm + mi * 16 + cr;
#pragma unroll
    for (int ni = 0; ni < 4; ++ni) {
      int col = wn + ni * 16 + cc;
      float obv = ob[col], pbv = pb[col];
#pragma unroll
      for (int r = 0; r < 4; ++r) {
        size_t idx = (size_t)(m0 + lrow + r) * 128 + col;
        float attv = accO[mi][ni][r] + obv;
        float pwv  = accP[mi][ni][r] + pbv;
        float hpre = 2.f * x[idx] + b2f(gp0[idx]) + attv * pwv * 0.01f;
        smem[(lrow + r) * 136 + col] = f2b(hpre);
      }
    }
  }
  __syncthreads();
  const int row = threadIdx.x >> 1, half = threadIdx.x & 1;
  const u16* rp = smem + row * 136 + half * 64;
  float s = 0.f, ss = 0.f;
#pragma unroll
  for (int j8 = 0; j8 < 8; ++j8) {
    short8 v = *(const short8*)(rp + j8 * 8);
#pragma unroll
    for (int j = 0; j < 8; ++j) { float f = b2f((u16)v[j]); s += f; ss += f * f; }
  }
  s += __shfl_xor(s, 1);
  ss += __shfl_xor(ss, 1);
  float mu = s * (1.f / 128.f);
  float rstd = rsqrtf(ss * (1.f / 128.f) - mu * mu + 1e-5f);
  size_t gbase = (size_t)(m0 + row) * 128 + half * 64;
#pragma unroll
  for (int j8 = 0; j8 < 8; ++j8) {
    short8 v = *(const short8*)(rp + j8 * 8);
    short8 o;
#pragma unroll
    for (int j = 0; j < 8; ++j) {
      int col = half * 64 + j8 * 8 + j;
      o[j] = (short)f2b((b2f((u16)v[j]) - mu) * rstd * sg[col] + sbt[col]);
    }
    *(short8*)(h16 + gbase + j8 * 8) = o;
  }
}

// ---------------------------------------------------------------------------
// Fused fc2 + LN2: out = LN(h16 + hid@fc2+b)
// ---------------------------------------------------------------------------
__global__ __launch_bounds__(256) void gemm_fc2ln(
    const u16* __restrict__ hid, const u16* __restrict__ fc2T, const float* __restrict__ fb,
    const u16* __restrict__ h16, const float* __restrict__ g, const float* __restrict__ be,
    float* __restrict__ out)
{
  __shared__ __align__(16) u16 smem[128 * 136];
  __shared__ float sg[128], sbt[128];
  u16* sA = smem;
  u16* sB = smem + 8192;
  if (threadIdx.x < 128) { sg[threadIdx.x] = g[threadIdx.x]; sbt[threadIdx.x] = be[threadIdx.x]; }
  const int m0 = blockIdx.x * 128;
  f32x4 accO[4][4] = {};
  mm_phase(hid, fc2T, 256, m0, sA, sB, accO);
  const int l = threadIdx.x & 63, wid = threadIdx.x >> 6;
  const int wm = (wid >> 1) << 6, wn = (wid & 1) << 6;
  const int cr = (l >> 4) << 2, cc = l & 15;
  __syncthreads();
#pragma unroll
  for (int mi = 0; mi < 4; ++mi) {
    int lrow = wm + mi * 16 + cr;
#pragma unroll
    for (int ni = 0; ni < 4; ++ni) {
      int col = wn + ni * 16 + cc;
      float fbv = fb[col];
#pragma unroll
      for (int r = 0; r < 4; ++r) {
        size_t idx = (size_t)(m0 + lrow + r) * 128 + col;
        float hpre = b2f(h16[idx]) + accO[mi][ni][r] + fbv;
        smem[(lrow + r) * 136 + col] = f2b(hpre);
      }
    }
  }
  __syncthreads();
  const int row = threadIdx.x >> 1, half = threadIdx.x & 1;
  const u16* rp = smem + row * 136 + half * 64;
  float s = 0.f, ss = 0.f;
#pragma unroll
  for (int j8 = 0; j8 < 8; ++j8) {
    short8 v = *(const short8*)(rp + j8 * 8);
#pragma unroll
    for (int j = 0; j < 8; ++j) { float f = b2f((u16)v[j]); s += f; ss += f * f; }
  }
  s += __shfl_xor(s, 1);
  ss += __shfl_xor(ss, 1);
  float mu = s * (1.f / 128.f);
  float rstd = rsqrtf(ss * (1.f / 128.f) - mu * mu + 1e-5f);
  size_t gbase = (size_t)(m0 + row) * 128 + half * 64;
#pragma unroll
  for (int j8 = 0; j8 < 8; ++j8) {
    short8 v = *(const short8*)(rp + j8 * 8);
    float4 o0, o1;
#pragma unroll
    for (int j = 0; j < 8; ++j) {
      int col = half * 64 + j8 * 8 + j;
      float y = (b2f((u16)v[j]) - mu) * rstd * sg[col] + sbt[col];
      if (j < 4) ((float*)&o0)[j] = y; else ((float*)&o1)[j - 4] = y;
    }
    *(float4*)(out + gbase + j8 * 8) = o0;
    *(float4*)(out + gbase + j8 * 8 + 4) = o1;
  }
}

// ---------------------------------------------------------------------------
// qknorm (q only): per (row, head g): inv = 1/max(||q_g||,1e-12)
// ---------------------------------------------------------------------------
__global__ __launch_bounds__(256) void qknorm(const u16* __restrict__ qkv,
                                              float* __restrict__ inv, size_t nidx)
{
  size_t idx = (size_t)blockIdx.x * 256 + threadIdx.x;
  if (idx >= nidx) return;
  size_t row = idx >> 3;
  int g = (int)(idx & 7);
  const u16* p = qkv + row * 384 + g * 16;
  short8 a = *(const short8*)p;
  short8 b = *(const short8*)(p + 8);
  float ss = 0.f;
#pragma unroll
  for (int j = 0; j < 8; ++j) {
    float f0 = b2f((u16)a[j]), f1 = b2f((u16)b[j]);
    ss += f0 * f0 + f1 * f1;
  }
  inv[idx] = 1.f / fmaxf(sqrtf(ss), 1e-12f);
}

__global__ __launch_bounds__(256) void cvt_f32_bf16(const float* __restrict__ src,
                                                    u16* __restrict__ dst, size_t n8)
{
  size_t i = (size_t)blockIdx.x * 256 + threadIdx.x;
  if (i >= n8) return;
  const float4* s = (const float4*)src;
  float4 u = s[i * 2], v = s[i * 2 + 1];
  short8 o;
  o[0] = (short)f2b(u.x); o[1] = (short)f2b(u.y);
  o[2] = (short)f2b(u.z); o[3] = (short)f2b(u.w);
  o[4] = (short)f2b(v.x); o[5] = (short)f2b(v.y);
  o[6] = (short)f2b(v.z); o[7] = (short)f2b(v.w);
  *(short8*)(dst + i * 8) = o;
}

__global__ __launch_bounds__(256) void transpose_cvt(const float* __restrict__ src,
                                                     u16* __restrict__ dst,
                                                     int R, int C)
{
  __shared__ u16 tile[64][65];
  const int tid = threadIdx.x;
  src += (size_t)blockIdx.z * R * C;
  dst += (size_t)blockIdx.z * R * C;
  const int c0 = blockIdx.x * 64, r0 = blockIdx.y * 64;
  const int tx = tid & 63, ty = tid >> 6;
#pragma unroll
  for (int i = 0; i < 64; i += 4)
    tile[ty + i][tx] = f2b(src[(size_t)(r0 + ty + i) * C + c0 + tx]);
  __syncthreads();
#pragma unroll
  for (int i = 0; i < 64; i += 4)
    dst[(size_t)(c0 + ty + i) * R + r0 + tx] = tile[tx][ty + i];
}

// x (f32 [512][128] per bt) -> xb (bf16) AND xT (bf16 transposed)
__global__ __launch_bounds__(256) void cvt_transpose_x(const float* __restrict__ src,
                                                       u16* __restrict__ xb,
                                                       u16* __restrict__ xT)
{
  __shared__ u16 tile[64][65];
  const int tid = threadIdx.x;
  const size_t zo = (size_t)blockIdx.z * Nn * Dd;
  src += zo; xb += zo; xT += zo;
  const int c0 = blockIdx.x * 64, r0 = blockIdx.y * 64;
  const int tx = tid & 63, ty = tid >> 6;
#pragma unroll
  for (int i = 0; i < 64; i += 4) {
    u16 b = f2b(src[(size_t)(r0 + ty + i) * Dd + c0 + tx]);
    tile[ty + i][tx] = b;
    xb[(size_t)(r0 + ty + i) * Dd + c0 + tx] = b;
  }
  __syncthreads();
#pragma unroll
  for (int i = 0; i < 64; i += 4)
    xT[(size_t)(c0 + ty + i) * Nn + r0 + tx] = tile[tx][ty + i];
}

// ---------------------------------------------------------------------------
// Spatial stats via MFMA (k-norm inline): kvs[bt][h][m][d]; ksum[m].
// ---------------------------------------------------------------------------
__global__ __launch_bounds__(256) void spatial_stats(const u16* __restrict__ qkv,
                                                     float* __restrict__ kvs,
                                                     float* __restrict__ ksum)
{
  __shared__ u16 sKT[16 * 512];
  __shared__ u16 sVT[16 * 512];
  __shared__ float red[4][16][16];
  __shared__ float red2[4][16];
  const int bt = blockIdx.x, h = blockIdx.y;
  const int tid = threadIdx.x;

  u16 kr[2][16], vr[2][16];
#pragma unroll
  for (int r = 0; r < 2; ++r) {
    int n = tid * 2 + r;
    size_t base = ((size_t)bt * 512 + n) * 384;
    short8 k0 = *(const short8*)(qkv + base + 128 + h * 16);
    short8 k1 = *(const short8*)(qkv + base + 136 + h * 16);
    short8 v0 = *(const short8*)(qkv + base + 256 + h * 16);
    short8 v1 = *(const short8*)(qkv + base + 264 + h * 16);
    float kf[16];
    float ssum = 0.f;
#pragma unroll
    for (int j = 0; j < 8; ++j) {
      kf[j] = b2f((u16)k0[j]); kf[j + 8] = b2f((u16)k1[j]);
      vr[r][j] = (u16)v0[j];   vr[r][j + 8] = (u16)v1[j];
      ssum += kf[j] * kf[j] + kf[j + 8] * kf[j + 8];
    }
    float inv = 1.f / fmaxf(sqrtf(ssum), 1e-12f);
#pragma unroll
    for (int j = 0; j < 16; ++j) kr[r][j] = f2b(kf[j] * inv);
  }
#pragma unroll
  for (int m = 0; m < 16; ++m) {
    unsigned pk = (unsigned)kr[0][m] | ((unsigned)kr[1][m] << 16);
    unsigned pv = (unsigned)vr[0][m] | ((unsigned)vr[1][m] << 16);
    int wa = ((m << 10) + (tid << 2)) ^ ((m & 7) << 4);
    *(unsigned*)((char*)sKT + wa) = pk;
    *(unsigned*)((char*)sVT + wa) = pv;
  }
  __syncthreads();

  const int l = tid & 63, w = tid >> 6;
  const int fr = l & 15, tq = l >> 4;
  short8 ones;
#pragma unroll
  for (int j = 0; j < 8; ++j) ones[j] = (short)0x3F80;
  f32x4 acc = {}, acs = {};
#pragma unroll
  for (int kk = 0; kk < 4; ++kk) {
    int noff = w * 128 + kk * 32 + tq * 8;
    int ra = ((fr << 10) + (noff << 1)) ^ ((fr & 7) << 4);
    short8 afr = *(const short8*)((const char*)sKT + ra);
    short8 bfr = *(const short8*)((const char*)sVT + ra);
    acc = __builtin_amdgcn_mfma_f32_16x16x32_bf16(afr, bfr, acc, 0, 0, 0);
    acs = __builtin_amdgcn_mfma_f32_16x16x32_bf16(afr, ones, acs, 0, 0, 0);
  }
#pragma unroll
  for (int r = 0; r < 4; ++r) red[w][tq * 4 + r][fr] = acc[r];
  if (fr == 0) {
#pragma unroll
    for (int r = 0; r < 4; ++r) red2[w][tq * 4 + r] = acs[r];
  }
  __syncthreads();
  const size_t o = (size_t)bt * 8 + h;
  {
    int m = tid >> 4, d = tid & 15;
    float s = red[0][m][d] + red[1][m][d] + red[2][m][d] + red[3][m][d];
    kvs[o * 256 + m * 16 + d] = s;
  }
  if (tid < 16) {
    float s = red2[0][tid] + red2[1][tid] + red2[2][tid] + red2[3][tid];
    ksum[o * 16 + tid] = s;
  }
}

// ---------------------------------------------------------------------------
// Temporal stats via MFMA (k-norm inline via paired shfl): kvt[b,n][m][c].
// ---------------------------------------------------------------------------
__global__ __launch_bounds__(256) void temporal_stats(const u16* __restrict__ qkv,
                                                      float* __restrict__ kvt,
                                                      float* __restrict__ kst)
{
  __shared__ u16 sKT[128 * 32];
  __shared__ u16 sVT[128 * 32];
  const int nn = blockIdx.x, b = blockIdx.y;
  const int tid = threadIdx.x;
  if (tid < 128) {
    short8 z = {};
    int wa = ((tid << 6) + 48) ^ ((tid & 3) << 4);
    *(short8*)((char*)sKT + wa) = z;
    *(short8*)((char*)sVT + wa) = z;
  }
  for (int idx = tid; idx < 384; idx += 256) {
    int t = idx >> 4, c8 = idx & 15;
    size_t rowg = ((size_t)(b * 24 + t) * 512) + nn;
    short8 kv = *(const short8*)(qkv + rowg * 384 + 128 + c8 * 8);
    short8 vv = *(const short8*)(qkv + rowg * 384 + 256 + c8 * 8);
    float kf[8];
    float ssum = 0.f;
#pragma unroll
    for (int j = 0; j < 8; ++j) { kf[j] = b2f((u16)kv[j]); ssum += kf[j] * kf[j]; }
    ssum += __shfl_xor(ssum, 1);   // partner lane = other half of this head
    float inv = 1.f / fmaxf(sqrtf(ssum), 1e-12f);
#pragma unroll
    for (int j = 0; j < 8; ++j) {
      int c = c8 * 8 + j;
      int wa = ((c << 6) + (t << 1)) ^ ((c & 3) << 4);
      *(u16*)((char*)sKT + wa) = f2b(kf[j] * inv);
      *(u16*)((char*)sVT + wa) = (u16)vv[j];
    }
  }
  __syncthreads();
  const int l = tid & 63, w = tid >> 6;
  const int fr = l & 15, tq = l >> 4;
  const size_t nb = (size_t)b * 512 + nn;
  short8 ones;
#pragma unroll
  for (int j = 0; j < 8; ++j) ones[j] = (short)0x3F80;
#pragma unroll
  for (int hi = 0; hi < 2; ++hi) {
    int h = w * 2 + hi;
    int c = h * 16 + fr;
    int ra = ((c << 6) + (tq << 4)) ^ ((c & 3) << 4);
    short8 afr = *(const short8*)((const char*)sKT + ra);
    short8 bfr = *(const short8*)((const char*)sVT + ra);
    f32x4 z = {};
    f32x4 acc = __builtin_amdgcn_mfma_f32_16x16x32_bf16(afr, bfr, z, 0, 0, 0);
    f32x4 acs = __builtin_amdgcn_mfma_f32_16x16x32_bf16(afr, ones, z, 0, 0, 0);
#pragma unroll
    for (int r = 0; r < 4; ++r)
      kvt[nb * 2048 + (size_t)(tq * 4 + r) * 128 + h * 16 + fr] = acc[r];
    if (fr == 0) {
#pragma unroll
      for (int r = 0; r < 4; ++r)
        kst[(nb * 8 + h) * 16 + tq * 4 + r] = acs[r];
    }
  }
}

// ---------------------------------------------------------------------------
// Apply: grid (Nn, CB, 3); block = 2 t-halves x 128 cl.
// Each thread computes BOTH spatial and temporal outputs for its (n, cl, t).
// ---------------------------------------------------------------------------
__global__ __launch_bounds__(256) void attn_apply(const u16* __restrict__ qkv,
                                                  const float* __restrict__ qkn,
                                                  const float* __restrict__ kvs,
                                                  const float* __restrict__ kss,
                                                  const float* __restrict__ kvt,
                                                  const float* __restrict__ kst,
                                                  u16* __restrict__ out_cat)
{
  __shared__ float s_kvt[2048];
  __shared__ float s_kst[8][16];
  const int nn = blockIdx.x, b = blockIdx.y;
  const int tid = threadIdx.x;
  const size_t nb = (size_t)b * 512 + nn;
  for (int i = tid; i < 2048; i += 256) s_kvt[i] = kvt[nb * 2048 + i];
  if (tid < 128) s_kst[tid >> 4][tid & 15] = kst[nb * 128 + tid];
  __syncthreads();
  const int sub = tid >> 7, cl = tid & 127;
  const int hh = cl >> 4, d = cl & 15;
  const int tbase = blockIdx.z * 8 + sub * 4;
  const float kst_hd = s_kst[hh][d];
  for (int ti = 0; ti < 4; ++ti) {
    const int t = tbase + ti;
    const size_t row = ((size_t)(b * 24 + t) * 512) + nn;
    const u16* qp = qkv + row * 384 + hh * 16;
    short8 q0 = *(const short8*)qp;
    short8 q1 = *(const short8*)(qp + 8);
    const float inv = qkn[row * 8 + hh];
    float qf[16];
#pragma unroll
    for (int j = 0; j < 8; ++j) {
      qf[j] = b2f((u16)q0[j]);
      qf[j + 8] = b2f((u16)q1[j]);
    }
    const size_t hb = (size_t)(b * 24 + t) * 8 + hh;
    const float* Mm = kvs + hb * 256;
    float accs = 0.f, acct = 0.f;
#pragma unroll
    for (int mI = 0; mI < 16; ++mI) {
      accs = fmaf(qf[mI], Mm[mI * 16 + d], accs);
      acct = fmaf(qf[mI], s_kvt[mI * 128 + cl], acct);
    }
    float dps = qf[d] * kss[hb * 16 + d];
    float dpt = qf[d] * kst_hd;
    dps += __shfl_xor(dps, 1);  dpt += __shfl_xor(dpt, 1);
    dps += __shfl_xor(dps, 2);  dpt += __shfl_xor(dpt, 2);
    dps += __shfl_xor(dps, 4);  dpt += __shfl_xor(dpt, 4);
    dps += __shfl_xor(dps, 8);  dpt += __shfl_xor(dpt, 8);
    float vv = b2f(qkv[row * 384 + 256 + cl]);
    out_cat[row * 256 + cl]       = f2b((accs * inv + 512.f * vv) / (dps * inv + 512.f));
    out_cat[row * 256 + 128 + cl] = f2b((acct * inv + 24.f * vv) / (dpt * inv + 24.f));
  }
}

extern "C" void kernel_launch(void* const* d_in, const int* in_sizes, int n_in,
                              void* d_out, int out_size, void* d_ws, size_t ws_size,
                              hipStream_t stream)
{
  const float* x      = (const float*)d_in[0];
  const float* graph  = (const float*)d_in[1];
  const float* qkv_w0 = (const float*)d_in[2];
  const float* out_w0 = (const float*)d_in[3];
  const float* out_b0 = (const float*)d_in[4];
  const float* pw_w0  = (const float*)d_in[5];
  const float* pw_b0  = (const float*)d_in[6];
  const float* qkv_w1 = (const float*)d_in[7];
  const float* out_w1 = (const float*)d_in[8];
  const float* out_b1 = (const float*)d_in[9];
  const float* pw_w1  = (const float*)d_in[10];
  const float* pw_b1  = (const float*)d_in[11];
  const float* fc1_w  = (const float*)d_in[12];
  const float* fc1_b  = (const float*)d_in[13];
  const float* fc2_w  = (const float*)d_in[14];
  const float* fc2_b  = (const float*)d_in[15];
  const float* ln1_g  = (const float*)d_in[16];
  const float* ln1_b  = (const float*)d_in[17];
  const float* ln2_g  = (const float*)d_in[18];
  const float* ln2_b  = (const float*)d_in[19];
  float* out = (float*)d_out;

  auto al = [](size_t v) { return (v + 255) & ~(size_t)255; };
  const size_t Rb = 12288;
  const size_t fixed = al((size_t)Tt * Nn * Nn * 2) + 2 * al((size_t)384 * 128 * 2)
                     + 2 * al((size_t)128 * 256 * 2) + 2 * al((size_t)128 * 128 * 2)
                     + al((size_t)256 * 128 * 2) + al((size_t)128 * 256 * 2);
  const size_t perb = al(Rb * 768) + al(Rb * 512) + 4 * al(Rb * 256) + al(Rb * 32)
                    + al((size_t)Tt * 8 * 256 * 4) + al((size_t)Tt * 8 * 16 * 4)
                    + al((size_t)Nn * 8 * 256 * 4) + al((size_t)Nn * 8 * 16 * 4);
  int CB = 8;
  while (CB > 1 && fixed + (size_t)CB * perb > ws_size) CB >>= 1;
  const size_t Mc = (size_t)CB * Rb;

  char* cur = (char*)d_ws;
  auto alloc = [&](size_t bytes) { char* p = cur; cur += (bytes + 255) & ~(size_t)255; return p; };
  u16* g_b16 = (u16*)alloc((size_t)Tt * Nn * Nn * 2);
  u16* qkvT0 = (u16*)alloc((size_t)384 * 128 * 2);
  u16* qkvT1 = (u16*)alloc((size_t)384 * 128 * 2);
  u16* outT0 = (u16*)alloc((size_t)128 * 256 * 2);
  u16* outT1 = (u16*)alloc((size_t)128 * 256 * 2);
  u16* pwT0  = (u16*)alloc((size_t)128 * 128 * 2);
  u16* pwT1  = (u16*)alloc((size_t)128 * 128 * 2);
  u16* fc1T  = (u16*)alloc((size_t)256 * 128 * 2);
  u16* fc2T  = (u16*)alloc((size_t)128 * 256 * 2);
  u16* qkvb  = (u16*)alloc(Mc * 768);
  u16* catb  = (u16*)alloc(Mc * 512);
  u16* x1b   = (u16*)alloc(Mc * 256);
  u16* att0  = (u16*)alloc(Mc * 256);
  u16* xb    = (u16*)alloc(Mc * 256);
  u16* xTgp  = (u16*)alloc(Mc * 256);
  float* qkn = (float*)alloc(Mc * 32);
  float* kvs = (float*)alloc((size_t)CB * Tt * 8 * 256 * 4);
  float* kss = (float*)alloc((size_t)CB * Tt * 8 * 16 * 4);
  float* kvt = (float*)alloc((size_t)CB * Nn * 8 * 256 * 4);
  float* kst = (float*)alloc((size_t)CB * Nn * 8 * 16 * 4);

  dim3 blk(256);
  cvt_f32_bf16<<<dim3((Tt * Nn * Nn / 8 + 255) / 256), blk, 0, stream>>>(
      graph, g_b16, (size_t)Tt * Nn * Nn / 8);
  transpose_cvt<<<dim3(6, 2, 1), blk, 0, stream>>>(qkv_w0, qkvT0, 128, 384);
  transpose_cvt<<<dim3(6, 2, 1), blk, 0, stream>>>(qkv_w1, qkvT1, 128, 384);
  transpose_cvt<<<dim3(2, 4, 1), blk, 0, stream>>>(out_w0, outT0, 256, 128);
  transpose_cvt<<<dim3(2, 4, 1), blk, 0, stream>>>(out_w1, outT1, 256, 128);
  transpose_cvt<<<dim3(2, 2, 1), blk, 0, stream>>>(pw_w0, pwT0, 128, 128);
  transpose_cvt<<<dim3(2, 2, 1), blk, 0, stream>>>(pw_w1, pwT1, 128, 128);
  transpose_cvt<<<dim3(4, 2, 1), blk, 0, stream>>>(fc1_w, fc1T, 128, 256);
  transpose_cvt<<<dim3(2, 4, 1), blk, 0, stream>>>(fc2_w, fc2T, 256, 128);

  const int MB = (int)(Mc / 128);
  const int nchunk = Bb / CB;
  for (int c = 0; c < nchunk; ++c) {
    const size_t off = (size_t)c * Mc * 128;
    const float* xc = x + off;
    float* outc = out + off;

    cvt_transpose_x<<<dim3(2, 8, CB * Tt), blk, 0, stream>>>(xc, xb, xTgp);
    gemm_mfma_graph<<<dim3(1, 4, CB * Tt), blk, 0, stream>>>(g_b16, xTgp, x1b);

    // ----- layer 0 -----
    gemm_mfma_k<1, 0><<<dim3(3, MB), blk, 0, stream>>>(xb, qkvT0, nullptr, qkvb, 384, 128);
    qknorm<<<dim3((unsigned)(Mc / 32)), blk, 0, stream>>>(qkvb, qkn, Mc * 8);
    spatial_stats<<<dim3(CB * Tt, Hh), blk, 0, stream>>>(qkvb, kvs, kss);
    temporal_stats<<<dim3(Nn, CB), blk, 0, stream>>>(qkvb, kvt, kst);
    attn_apply<<<dim3(Nn, CB, 3), blk, 0, stream>>>(qkvb, qkn, kvs, kss, kvt, kst, catb);
    gemm_og0<<<dim3(MB), blk, 0, stream>>>(catb, outT0, out_b0, xb, pwT0, pw_b0,
                                           xTgp, att0);   // gp0 = xTgp (xT dead)

    // ----- layer 1 -----
    gemm_mfma_k<1, 0><<<dim3(3, MB), blk, 0, stream>>>(x1b, qkvT1, nullptr, qkvb, 384, 128);
    qknorm<<<dim3((unsigned)(Mc / 32)), blk, 0, stream>>>(qkvb, qkn, Mc * 8);
    spatial_stats<<<dim3(CB * Tt, Hh), blk, 0, stream>>>(qkvb, kvs, kss);
    temporal_stats<<<dim3(Nn, CB), blk, 0, stream>>>(qkvb, kvt, kst);
    attn_apply<<<dim3(Nn, CB, 3), blk, 0, stream>>>(qkvb, qkn, kvs, kss, kvt, kst, catb);
    u16* h16 = qkvb;   // qkvb dead after apply1
    gemm_og1<<<dim3(MB), blk, 0, stream>>>(catb, outT1, out_b1, att0, pwT1, pw_b1,
                                           xTgp, xc, ln1_g, ln1_b, h16);

    // ----- MLP + LN2 -----
    gemm_mfma_k<1, 1><<<dim3(2, MB), blk, 0, stream>>>(h16, fc1T, fc1_b, catb, 256, 128);
    gemm_fc2ln<<<dim3(MB), blk, 0, stream>>>(catb, fc2T, fc2_b, h16, ln2_g, ln2_b, outc);
  }

  (void)in_sizes; (void)n_in; (void)out_size;
}